// Round 11
// baseline (2238.604 us; speedup 1.0000x reference)
//
#include <hip/hip_runtime.h>
#include <hip/hip_bf16.h>
#include <cstdint>
#include <cstddef>

#define VOCAB 10000
#define EMB   1024
#define HID   1024
#define BATCH 32
#define SEQ   256
#define ROWS  (SEQ*BATCH)   // 8192
#define SNBLK 16            // scan workers; 64 cols each
#define PB    128           // ctrl: published-xcc base (ints)
#define FB    1024          // ctrl: step-flag base; flag[slot][wid] at FB+slot*64+wid*16
#define RST   68            // red stride (floats)

typedef __attribute__((ext_vector_type(8))) short short8;
typedef __attribute__((ext_vector_type(4))) float f32x4;

static __device__ __forceinline__ unsigned short f2bf(float f){
  unsigned int u = __builtin_bit_cast(unsigned int, f);
  u += 0x7fffu + ((u >> 16) & 1u);
  return (unsigned short)(u >> 16);
}

// ---------- transpose-convert: fp32 src[K][N] -> bf16 dst[N][K] ----------
__global__ void k_transpose(const float* __restrict__ src, unsigned short* __restrict__ dst,
                            int K, int N){
  __shared__ unsigned short tile[64][65];
  int n0 = blockIdx.x * 64, k0 = blockIdx.y * 64;
  int tid = threadIdx.x;
  #pragma unroll
  for (int it = 0; it < 16; ++it){
    int e = tid + it*256;
    int i = e >> 6, j = e & 63;
    float v = 0.f;
    if (k0 + i < K && n0 + j < N) v = src[(size_t)(k0+i)*N + n0 + j];
    tile[j][i] = f2bf(v);
  }
  __syncthreads();
  #pragma unroll
  for (int it = 0; it < 16; ++it){
    int e = tid + it*256;
    int r = e >> 6, c = e & 63;
    if (n0 + r < N && k0 + c < K)
      dst[(size_t)(n0+r)*K + k0 + c] = tile[r][c];
  }
}

// ---------- embedding gather + fp32->bf16 ----------
__global__ void k_gather(const int* __restrict__ seq, const float* __restrict__ emb,
                         unsigned short* __restrict__ X){
  int r = blockIdx.x;                 // r = t*32 + b
  int t = r >> 5, b = r & 31;
  int idx = seq[b*SEQ + t];
  const float4* s = (const float4*)(emb + (size_t)idx * EMB);
  float4 v = s[threadIdx.x];
  ushort4 o;
  o.x = f2bf(v.x); o.y = f2bf(v.y); o.z = f2bf(v.z); o.w = f2bf(v.w);
  ((ushort4*)(X + (size_t)r * EMB))[threadIdx.x] = o;
}

// ---------- GEMM: C[M][ldc] = A[M][K](bf16) * BT[Npad][K](bf16)^T + bias ----------
template<bool OUT_BF16>
__global__ __launch_bounds__(256) void k_gemm_bt(
    const unsigned short* __restrict__ A,
    const unsigned short* __restrict__ BT,
    const float* __restrict__ bias,
    void* __restrict__ C, int M, int Nreal, int K, int ldc){
  __shared__ __align__(16) unsigned short As[128][40];
  __shared__ __align__(16) unsigned short Bs[128][40];
  int tid  = threadIdx.x;
  int lane = tid & 63, wid = tid >> 6;
  int wr = (wid >> 1) * 64, wc = (wid & 1) * 64;
  int m0 = blockIdx.y * 128, n0 = blockIdx.x * 128;
  int la = lane & 15, ko = (lane >> 4) * 8;
  f32x4 acc[4][4] = {};
  for (int k0 = 0; k0 < K; k0 += 32){
    #pragma unroll
    for (int q = tid; q < 512; q += 256){
      int row = q >> 2, kc = (q & 3) * 8;
      *(uint4*)&As[row][kc] = *(const uint4*)(A  + (size_t)(m0+row)*K + k0 + kc);
      *(uint4*)&Bs[row][kc] = *(const uint4*)(BT + (size_t)(n0+row)*K + k0 + kc);
    }
    __syncthreads();
    short8 av[4], bv[4];
    #pragma unroll
    for (int f = 0; f < 4; ++f){
      av[f] = *(const short8*)&As[wr + f*16 + la][ko];
      bv[f] = *(const short8*)&Bs[wc + f*16 + la][ko];
    }
    #pragma unroll
    for (int mf = 0; mf < 4; ++mf)
      #pragma unroll
      for (int nf = 0; nf < 4; ++nf)
        acc[mf][nf] = __builtin_amdgcn_mfma_f32_16x16x32_bf16(av[mf], bv[nf], acc[mf][nf], 0, 0, 0);
    __syncthreads();
  }
  int dr = (lane >> 4) * 4, dc = lane & 15;
  #pragma unroll
  for (int mf = 0; mf < 4; ++mf){
    #pragma unroll
    for (int nf = 0; nf < 4; ++nf){
      int col = n0 + wc + nf*16 + dc;
      if (col >= Nreal) continue;
      float bb = bias[col];
      #pragma unroll
      for (int rg = 0; rg < 4; ++rg){
        int row = m0 + wr + mf*16 + dr + rg;
        float v = acc[mf][nf][rg] + bb;
        if (OUT_BF16) ((unsigned short*)C)[(size_t)row*ldc + col] = f2bf(v);
        else          ((float*)C)[(size_t)row*ldc + col] = v;
      }
    }
  }
}

// pin 8 short8 values live-in-register (single asm: one waitcnt, no interleave)
#define PIN8(a) asm volatile("" : "+v"((a)[0]),"+v"((a)[1]),"+v"((a)[2]),"+v"((a)[3]), \
                                   "+v"((a)[4]),"+v"((a)[5]),"+v"((a)[6]),"+v"((a)[7]))

// L2-executed flag read: always-failing CAS (cannot be elided to a cached load)
static __device__ __forceinline__ int flag_read_l2(int* p){
  int expected = -1;
  __hip_atomic_compare_exchange_strong(p, &expected, -1,
      __ATOMIC_RELAXED, __ATOMIC_RELAXED, __HIP_MEMORY_SCOPE_WORKGROUP);
  return expected;
}

// ---------- persistent scan: 16 colocated workers; L2-atomic flag sync ----------
__global__ __launch_bounds__(256, 1) void k_scan(
    const unsigned short* __restrict__ UT,   // [HID][HID] bf16, UT[n][k]
    const float* __restrict__ G0,            // [ROWS][HID] fp32 (includes b_gate)
    unsigned short* __restrict__ Hfull,      // [(32+ROWS)][HID] bf16, rows 0..31 zeroed
    int* ctrl){
  __shared__ float red[2][4][32][RST];       // 68 KB, double-buffered by t&1
  __shared__ int s_slot, s_fast;
  const int tid  = threadIdx.x;
  const int lane = tid & 63, wid = tid >> 6;

  // ---- election (r10 structure) + flag-zero via WG-exchange (fixes stale L2) ----
  if (tid == 0){
    int xcc;
    asm volatile("s_getreg_b32 %0, hwreg(HW_REG_XCC_ID)" : "=s"(xcc));
    xcc &= 0xff;
    int expected = 0;
    __hip_atomic_compare_exchange_strong(&ctrl[0], &expected, xcc + 1,
        __ATOMIC_ACQ_REL, __ATOMIC_ACQUIRE, __HIP_MEMORY_SCOPE_AGENT);
    int lead = (expected == 0) ? xcc : expected - 1;
    int ticket = -1;
    if (xcc == lead){
      ticket = __hip_atomic_fetch_add(&ctrl[32], 1, __ATOMIC_RELAXED, __HIP_MEMORY_SCOPE_AGENT);
    } else {
      for (int it = 0; it < 64; ++it){
        if (__hip_atomic_load(&ctrl[32], __ATOMIC_RELAXED, __HIP_MEMORY_SCOPE_AGENT) >= SNBLK) break;
        for (int j = 0; j < 4; ++j) __builtin_amdgcn_s_sleep(32);
      }
      if (__hip_atomic_load(&ctrl[32], __ATOMIC_RELAXED, __HIP_MEMORY_SCOPE_AGENT) < SNBLK)
        ticket = __hip_atomic_fetch_add(&ctrl[32], 1, __ATOMIC_RELAXED, __HIP_MEMORY_SCOPE_AGENT);
    }
    int slot = (ticket >= 0 && ticket < SNBLK) ? ticket : -1;
    int fast = 1;
    if (slot >= 0){
      // zero my 4 wave-flags AT THE L2 (WG-scope RMW corrects stale dirty lines)
      #pragma unroll
      for (int w = 0; w < 4; ++w)
        __hip_atomic_exchange(&ctrl[FB + slot*64 + w*16], 0,
                              __ATOMIC_RELAXED, __HIP_MEMORY_SCOPE_WORKGROUP);
      __hip_atomic_store(&ctrl[PB + slot], xcc + 1, __ATOMIC_RELEASE, __HIP_MEMORY_SCOPE_AGENT);
      for (int i = 0; i < SNBLK; ++i){
        int v;
        while ((v = __hip_atomic_load(&ctrl[PB + i], __ATOMIC_ACQUIRE, __HIP_MEMORY_SCOPE_AGENT)) == 0)
          __builtin_amdgcn_s_sleep(8);
        if (v - 1 != xcc) fast = 0;
      }
    }
    s_slot = slot; s_fast = fast;
  }
  __syncthreads();
  const int slot = s_slot, fastp = s_fast;
  if (slot < 0) return;
  const int n0 = slot * 64;

  const int q  = wid;                  // this wave's K-quarter
  const int la = lane & 15, kg = lane >> 4;
  const int b  = tid >> 3, nn = (tid & 7) * 8;

  // ---- B preload + per-iteration pin (as r10) ----
  short8 Br[4][8];
  #pragma unroll
  for (int cg = 0; cg < 4; ++cg)
    #pragma unroll
    for (int kc = 0; kc < 8; ++kc)
      Br[cg][kc] = *(const short8*)(UT + (size_t)(n0 + cg*16 + la)*HID + q*256 + kc*32 + kg*8);

  float creg[8];
  #pragma unroll
  for (int j = 0; j < 8; ++j) creg[j] = 0.f;
  float g0r[8];
  {
    const float* gp = G0 + (size_t)b * HID + n0 + nn;
    float4 lo = *(const float4*)gp, hi = *(const float4*)(gp + 4);
    g0r[0]=lo.x; g0r[1]=lo.y; g0r[2]=lo.z; g0r[3]=lo.w;
    g0r[4]=hi.x; g0r[5]=hi.y; g0r[6]=hi.z; g0r[7]=hi.w;
  }

  for (int t = 0; t < SEQ; ++t){
    PIN8(Br[0]); PIN8(Br[1]); PIN8(Br[2]); PIN8(Br[3]);

    // ---- wait for peers' h_{t-1} ----
    if (t > 0){
      if (fastp){
        // every wave polls independently (no barrier): lane l -> flag l, L2 CAS
        int* fp = &ctrl[FB + (lane & 15)*64 + (lane >> 4)*16];
        int guard = 0;
        for (;;){
          int v = flag_read_l2(fp);
          if (__all(v >= t)) break;
          if (++guard > (1<<14)){
            if (lane == 0)
              __hip_atomic_fetch_or(&ctrl[64], 1, __ATOMIC_RELAXED, __HIP_MEMORY_SCOPE_AGENT);
            break;
          }
        }
      } else {
        if (wid == 0){
          const int* fp = &ctrl[FB + (lane & 15)*64 + (lane >> 4)*16];
          int guard = 0, dead = 0;
          for (;;){
            int v = __hip_atomic_load(fp, __ATOMIC_RELAXED, __HIP_MEMORY_SCOPE_AGENT);
            if (__all(v >= t)) break;
            if (++guard > (1<<15)) { dead = 1; break; }
          }
          if (dead && lane == 0)
            __hip_atomic_fetch_or(&ctrl[64], 1, __ATOMIC_RELAXED, __HIP_MEMORY_SCOPE_AGENT);
          __threadfence();
        }
        __syncthreads();
      }
    }

    // ---- A-loads: 16 b128 in one MLP burst + single batch pin ----
    const unsigned short* hpA = Hfull + (size_t)t*32*HID + (size_t)la*HID + q*256 + kg*8;
    const unsigned short* hpB = hpA + (size_t)16*HID;
    short8 A0[8], A1[8];
    #pragma unroll
    for (int kc = 0; kc < 8; ++kc){
      A0[kc] = *(const short8*)(hpA + kc*32);
      A1[kc] = *(const short8*)(hpB + kc*32);
    }
    asm volatile("" : "+v"(A0[0]),"+v"(A0[1]),"+v"(A0[2]),"+v"(A0[3]),
                      "+v"(A0[4]),"+v"(A0[5]),"+v"(A0[6]),"+v"(A0[7]),
                      "+v"(A1[0]),"+v"(A1[1]),"+v"(A1[2]),"+v"(A1[3]),
                      "+v"(A1[4]),"+v"(A1[5]),"+v"(A1[6]),"+v"(A1[7]));

    // ---- G0 prefetch for next step ----
    float4 gnlo, gnhi;
    {
      int tn = (t + 1 < SEQ) ? (t + 1) : t;
      const float* gp = G0 + ((size_t)tn*32 + b) * HID + n0 + nn;
      gnlo = *(const float4*)gp; gnhi = *(const float4*)(gp + 4);
    }

    // ---- pure-register MFMA stream ----
    f32x4 acc0[4] = {}, acc1[4] = {};
    #pragma unroll
    for (int kc = 0; kc < 8; ++kc)
      #pragma unroll
      for (int cg = 0; cg < 4; ++cg){
        acc0[cg] = __builtin_amdgcn_mfma_f32_16x16x32_bf16(A0[kc], Br[cg][kc], acc0[cg], 0, 0, 0);
        acc1[cg] = __builtin_amdgcn_mfma_f32_16x16x32_bf16(A1[kc], Br[cg][kc], acc1[cg], 0, 0, 0);
      }

    // ---- K-quarter partials -> red[t&1] ----
    const int par = t & 1;
    #pragma unroll
    for (int cg = 0; cg < 4; ++cg)
      #pragma unroll
      for (int rg = 0; rg < 4; ++rg){
        red[par][q][kg*4 + rg][cg*16 + la]      = acc0[cg][rg];
        red[par][q][16 + kg*4 + rg][cg*16 + la] = acc1[cg][rg];
      }
    __syncthreads();                     // the ONE barrier per step (red reduction)

    // ---- gates + h-write ----
    float4 q0lo = *(const float4*)&red[par][0][b][nn], q0hi = *(const float4*)&red[par][0][b][nn+4];
    float4 q1lo = *(const float4*)&red[par][1][b][nn], q1hi = *(const float4*)&red[par][1][b][nn+4];
    float4 q2lo = *(const float4*)&red[par][2][b][nn], q2hi = *(const float4*)&red[par][2][b][nn+4];
    float4 q3lo = *(const float4*)&red[par][3][b][nn], q3hi = *(const float4*)&red[par][3][b][nn+4];
    float gg[8] = {
      q0lo.x+q1lo.x+q2lo.x+q3lo.x+g0r[0], q0lo.y+q1lo.y+q2lo.y+q3lo.y+g0r[1],
      q0lo.z+q1lo.z+q2lo.z+q3lo.z+g0r[2], q0lo.w+q1lo.w+q2lo.w+q3lo.w+g0r[3],
      q0hi.x+q1hi.x+q2hi.x+q3hi.x+g0r[4], q0hi.y+q1hi.y+q2hi.y+q3hi.y+g0r[5],
      q0hi.z+q1hi.z+q2hi.z+q3hi.z+g0r[6], q0hi.w+q1hi.w+q2hi.w+q3hi.w+g0r[7] };
    short8 hv;
    #pragma unroll
    for (int j = 0; j < 8; ++j){
      float g  = gg[j];
      float e  = __expf(-g);
      float s  = __builtin_amdgcn_rcpf(1.f + e);
      float e2 = e * e;
      float tg = 2.f * __builtin_amdgcn_rcpf(1.f + e2) - 1.f;
      float cn = s * (creg[j] + tg);
      creg[j] = cn;
      float ec = __expf(-2.f * cn);
      float th = 2.f * __builtin_amdgcn_rcpf(1.f + ec) - 1.f;
      hv[j] = (short)f2bf(th * s);
    }
    *(short8*)(Hfull + ((size_t)(t+1)*32 + b) * HID + n0 + nn) = hv;

    // ---- publish own wave-flag: h-stores L2-acked, then L2 RMW (fast) / IC (slow) ----
    asm volatile("s_waitcnt vmcnt(0)" ::: "memory");
    if (fastp){
      if (lane == 0)
        __hip_atomic_exchange(&ctrl[FB + slot*64 + wid*16], t + 1,
                              __ATOMIC_RELAXED, __HIP_MEMORY_SCOPE_WORKGROUP);
    } else {
      __threadfence();
      if (lane == 0)
        __hip_atomic_store(&ctrl[FB + slot*64 + wid*16], t + 1,
                           __ATOMIC_RELAXED, __HIP_MEMORY_SCOPE_AGENT);
    }

    g0r[0]=gnlo.x; g0r[1]=gnlo.y; g0r[2]=gnlo.z; g0r[3]=gnlo.w;
    g0r[4]=gnhi.x; g0r[5]=gnhi.y; g0r[6]=gnhi.z; g0r[7]=gnhi.w;
  }

  // telemetry: slow path +1ms, any deadman +4ms (visible in dur_us)
  if (slot == 0 && tid == 0){
    long long spin = 0;
    if (!fastp) spin += 100000LL;
    if (__hip_atomic_load(&ctrl[64], __ATOMIC_RELAXED, __HIP_MEMORY_SCOPE_AGENT) != 0)
      spin += 400000LL;
    if (spin){
      long long t0 = __builtin_amdgcn_s_memrealtime();
      while (__builtin_amdgcn_s_memrealtime() - t0 < spin) {}
    }
  }
}

// ---------- ablation: identical core, 16 blocks, ZERO sync, 64 steps, dummy H ----------
// rocprof row = compute+load floor per step (x4 for 256-step equivalent).
__global__ __launch_bounds__(256, 1) void k_scan2(
    const unsigned short* __restrict__ UT,
    const float* __restrict__ G0,
    unsigned short* __restrict__ Hd){   // dummy ring of 64 rowblocks (X region)
  __shared__ float red[2][4][32][RST];
  const int tid  = threadIdx.x;
  const int lane = tid & 63, wid = tid >> 6;
  const int n0 = blockIdx.x * 64;
  const int q  = wid;
  const int la = lane & 15, kg = lane >> 4;
  const int b  = tid >> 3, nn = (tid & 7) * 8;

  short8 Br[4][8];
  #pragma unroll
  for (int cg = 0; cg < 4; ++cg)
    #pragma unroll
    for (int kc = 0; kc < 8; ++kc)
      Br[cg][kc] = *(const short8*)(UT + (size_t)(n0 + cg*16 + la)*HID + q*256 + kc*32 + kg*8);

  float creg[8];
  #pragma unroll
  for (int j = 0; j < 8; ++j) creg[j] = 0.f;
  float g0r[8];
  {
    const float* gp = G0 + (size_t)b * HID + n0 + nn;
    float4 lo = *(const float4*)gp, hi = *(const float4*)(gp + 4);
    g0r[0]=lo.x; g0r[1]=lo.y; g0r[2]=lo.z; g0r[3]=lo.w;
    g0r[4]=hi.x; g0r[5]=hi.y; g0r[6]=hi.z; g0r[7]=hi.w;
  }

  for (int t = 0; t < 64; ++t){
    PIN8(Br[0]); PIN8(Br[1]); PIN8(Br[2]); PIN8(Br[3]);
    const unsigned short* hpA = Hd + (size_t)(t & 63)*32*HID + (size_t)la*HID + q*256 + kg*8;
    const unsigned short* hpB = hpA + (size_t)16*HID;
    short8 A0[8], A1[8];
    #pragma unroll
    for (int kc = 0; kc < 8; ++kc){
      A0[kc] = *(const short8*)(hpA + kc*32);
      A1[kc] = *(const short8*)(hpB + kc*32);
    }
    asm volatile("" : "+v"(A0[0]),"+v"(A0[1]),"+v"(A0[2]),"+v"(A0[3]),
                      "+v"(A0[4]),"+v"(A0[5]),"+v"(A0[6]),"+v"(A0[7]),
                      "+v"(A1[0]),"+v"(A1[1]),"+v"(A1[2]),"+v"(A1[3]),
                      "+v"(A1[4]),"+v"(A1[5]),"+v"(A1[6]),"+v"(A1[7]));
    float4 gnlo, gnhi;
    {
      const float* gp = G0 + ((size_t)(t+1)*32 + b) * HID + n0 + nn;
      gnlo = *(const float4*)gp; gnhi = *(const float4*)(gp + 4);
    }
    f32x4 acc0[4] = {}, acc1[4] = {};
    #pragma unroll
    for (int kc = 0; kc < 8; ++kc)
      #pragma unroll
      for (int cg = 0; cg < 4; ++cg){
        acc0[cg] = __builtin_amdgcn_mfma_f32_16x16x32_bf16(A0[kc], Br[cg][kc], acc0[cg], 0, 0, 0);
        acc1[cg] = __builtin_amdgcn_mfma_f32_16x16x32_bf16(A1[kc], Br[cg][kc], acc1[cg], 0, 0, 0);
      }
    const int par = t & 1;
    #pragma unroll
    for (int cg = 0; cg < 4; ++cg)
      #pragma unroll
      for (int rg = 0; rg < 4; ++rg){
        red[par][q][kg*4 + rg][cg*16 + la]      = acc0[cg][rg];
        red[par][q][16 + kg*4 + rg][cg*16 + la] = acc1[cg][rg];
      }
    __syncthreads();
    float4 q0lo = *(const float4*)&red[par][0][b][nn], q0hi = *(const float4*)&red[par][0][b][nn+4];
    float4 q1lo = *(const float4*)&red[par][1][b][nn], q1hi = *(const float4*)&red[par][1][b][nn+4];
    float4 q2lo = *(const float4*)&red[par][2][b][nn], q2hi = *(const float4*)&red[par][2][b][nn+4];
    float4 q3lo = *(const float4*)&red[par][3][b][nn], q3hi = *(const float4*)&red[par][3][b][nn+4];
    float gg[8] = {
      q0lo.x+q1lo.x+q2lo.x+q3lo.x+g0r[0], q0lo.y+q1lo.y+q2lo.y+q3lo.y+g0r[1],
      q0lo.z+q1lo.z+q2lo.z+q3lo.z+g0r[2], q0lo.w+q1lo.w+q2lo.w+q3lo.w+g0r[3],
      q0hi.x+q1hi.x+q2hi.x+q3hi.x+g0r[4], q0hi.y+q1hi.y+q2hi.y+q3hi.y+g0r[5],
      q0hi.z+q1hi.z+q2hi.z+q3hi.z+g0r[6], q0hi.w+q1hi.w+q2hi.w+q3hi.w+g0r[7] };
    short8 hv;
    #pragma unroll
    for (int j = 0; j < 8; ++j){
      float g  = gg[j];
      float e  = __expf(-g);
      float s  = __builtin_amdgcn_rcpf(1.f + e);
      float e2 = e * e;
      float tg = 2.f * __builtin_amdgcn_rcpf(1.f + e2) - 1.f;
      float cn = s * (creg[j] + tg);
      creg[j] = cn;
      float ec = __expf(-2.f * cn);
      float th = 2.f * __builtin_amdgcn_rcpf(1.f + ec) - 1.f;
      hv[j] = (short)f2bf(th * s);
    }
    *(short8*)(Hd + ((size_t)((t+1) & 63)*32 + b) * HID + n0 + nn) = hv;
    g0r[0]=gnlo.x; g0r[1]=gnlo.y; g0r[2]=gnlo.z; g0r[3]=gnlo.w;
    g0r[4]=gnhi.x; g0r[5]=gnhi.y; g0r[6]=gnhi.z; g0r[7]=gnhi.w;
  }
}

extern "C" void kernel_launch(void* const* d_in, const int* in_sizes, int n_in,
                              void* d_out, int out_size, void* d_ws, size_t ws_size,
                              hipStream_t stream){
  (void)in_sizes; (void)n_in; (void)out_size;
  const int*   seq     = (const int*)d_in[0];
  const float* emb     = (const float*)d_in[1];
  const float* w_gate  = (const float*)d_in[2];
  const float* b_gate  = (const float*)d_in[3];
  const float* w_out   = (const float*)d_in[4];
  const float* b_out   = (const float*)d_in[5];
  const float* w_dense = (const float*)d_in[6];
  const float* b_dense = (const float*)d_in[7];
  float* out = (float*)d_out;

  const int NPAD_D = 10112;   // 79 * 128
  char* ws = (char*)d_ws;
  size_t off = 0;
  auto alloc = [&](size_t bytes){ size_t o = off; off += (bytes + 255) & ~(size_t)255; return o; };
  size_t off_W1T = alloc((size_t)2*HID*HID);
  size_t off_UT  = alloc((size_t)2*HID*HID);
  size_t off_WoT = alloc((size_t)2*HID*HID);
  size_t off_WdT = alloc((size_t)2*NPAD_D*HID);
  size_t off_X   = alloc((size_t)2*ROWS*EMB);             // bf16; dummy-H / YS reuse
  size_t off_G0  = alloc((size_t)4*ROWS*HID);
  size_t off_H   = alloc((size_t)2*(ROWS+32)*HID);
  size_t off_ctl = alloc(8192);
  if (ws_size < off) return;

  unsigned short* W1T = (unsigned short*)(ws + off_W1T);
  unsigned short* UT  = (unsigned short*)(ws + off_UT);
  unsigned short* WoT = (unsigned short*)(ws + off_WoT);
  unsigned short* WdT = (unsigned short*)(ws + off_WdT);
  unsigned short* X   = (unsigned short*)(ws + off_X);
  unsigned short* YS  = (unsigned short*)(ws + off_X);
  unsigned short* Hd  = (unsigned short*)(ws + off_X);
  float*          G0  = (float*)(ws + off_G0);
  unsigned short* Hf  = (unsigned short*)(ws + off_H);
  int*            ctl = (int*)(ws + off_ctl);

  hipMemsetAsync(ctl, 0, 8192, stream);
  hipMemsetAsync(WdT + (size_t)10000*HID, 0, (size_t)2*(NPAD_D-10000)*HID, stream);
  hipMemsetAsync(Hf, 0, (size_t)2*32*HID, stream);

  k_transpose<<<dim3(16,16), 256, 0, stream>>>(w_gate,           W1T, HID, HID);
  k_transpose<<<dim3(16,16), 256, 0, stream>>>(w_gate + HID*HID, UT,  HID, HID);
  k_transpose<<<dim3(16,16), 256, 0, stream>>>(w_out,            WoT, HID, HID);
  k_transpose<<<dim3(157,16),256, 0, stream>>>(w_dense,          WdT, HID, VOCAB);

  k_gather<<<ROWS, 256, 0, stream>>>(seq, emb, X);

  // G0 = X @ W1 + b_gate  (fp32 out)
  k_gemm_bt<false><<<dim3(8,64), 256, 0, stream>>>(X, W1T, b_gate, G0, ROWS, HID, EMB, HID);

  // real sequential scan (16 workers elected from 256 candidate blocks)
  k_scan<<<256, 256, 0, stream>>>(UT, G0, Hf, ctl);

  // ablation: sync-free core clone, 64 steps, dummy H in X region (overwritten below)
  k_scan2<<<SNBLK, 256, 0, stream>>>(UT, G0, Hd);

  // ys = H @ w_out + b_out  (bf16 out, into X region)
  k_gemm_bt<true><<<dim3(8,64), 256, 0, stream>>>(Hf + (size_t)32*HID, WoT, b_out, YS,
                                                  ROWS, HID, HID, HID);

  // logits = ys @ w_dense + b_dense (fp32 out)
  k_gemm_bt<false><<<dim3(79,64), 256, 0, stream>>>(YS, WdT, b_dense, out,
                                                    ROWS, VOCAB, HID, VOCAB);
}

// Round 14
// 1488.943 us; speedup vs baseline: 1.5035x; 1.5035x over previous
//
#include <hip/hip_runtime.h>
#include <hip/hip_bf16.h>
#include <cstdint>
#include <cstddef>

#define VOCAB 10000
#define EMB   1024
#define HID   1024
#define BATCH 32
#define SEQ   256
#define ROWS  (SEQ*BATCH)   // 8192
#define SNBLK 16            // scan workers; 64 cols each
#define PB    128           // ctrl: published-xcc base (ints)
#define FB    1024          // ctrl: step-flag base; flag[slot][wid] at FB+slot*64+wid*16
#define RST   68            // red stride (floats)

typedef __attribute__((ext_vector_type(8))) short short8;
typedef __attribute__((ext_vector_type(4))) float f32x4;

static __device__ __forceinline__ unsigned short f2bf(float f){
  unsigned int u = __builtin_bit_cast(unsigned int, f);
  u += 0x7fffu + ((u >> 16) & 1u);
  return (unsigned short)(u >> 16);
}

// ---------- transpose-convert: fp32 src[K][N] -> bf16 dst[N][K] ----------
__global__ void k_transpose(const float* __restrict__ src, unsigned short* __restrict__ dst,
                            int K, int N){
  __shared__ unsigned short tile[64][65];
  int n0 = blockIdx.x * 64, k0 = blockIdx.y * 64;
  int tid = threadIdx.x;
  #pragma unroll
  for (int it = 0; it < 16; ++it){
    int e = tid + it*256;
    int i = e >> 6, j = e & 63;
    float v = 0.f;
    if (k0 + i < K && n0 + j < N) v = src[(size_t)(k0+i)*N + n0 + j];
    tile[j][i] = f2bf(v);
  }
  __syncthreads();
  #pragma unroll
  for (int it = 0; it < 16; ++it){
    int e = tid + it*256;
    int r = e >> 6, c = e & 63;
    if (n0 + r < N && k0 + c < K)
      dst[(size_t)(n0+r)*K + k0 + c] = tile[r][c];
  }
}

// ---------- embedding gather + fp32->bf16 ----------
__global__ void k_gather(const int* __restrict__ seq, const float* __restrict__ emb,
                         unsigned short* __restrict__ X){
  int r = blockIdx.x;                 // r = t*32 + b
  int t = r >> 5, b = r & 31;
  int idx = seq[b*SEQ + t];
  const float4* s = (const float4*)(emb + (size_t)idx * EMB);
  float4 v = s[threadIdx.x];
  ushort4 o;
  o.x = f2bf(v.x); o.y = f2bf(v.y); o.z = f2bf(v.z); o.w = f2bf(v.w);
  ((ushort4*)(X + (size_t)r * EMB))[threadIdx.x] = o;
}

// ---------- GEMM: C[M][ldc] = A[M][K](bf16) * BT[Npad][K](bf16)^T + bias ----------
// 128x128 tile, BK=32, global_load_lds(16B) staging into LINEAR LDS (m97 pattern).
template<bool OUT_BF16>
__global__ __launch_bounds__(256) void k_gemm_bt(
    const unsigned short* __restrict__ A,
    const unsigned short* __restrict__ BT,
    const float* __restrict__ bias,
    void* __restrict__ C, int M, int Nreal, int K, int ldc){
  __shared__ __align__(16) unsigned short As[128*32];   // 8 KB linear [row][32]
  __shared__ __align__(16) unsigned short Bs[128*32];
  int tid  = threadIdx.x;
  int lane = tid & 63, wid = tid >> 6;
  int wr = (wid >> 1) * 64, wc = (wid & 1) * 64;
  int m0 = blockIdx.y * 128, n0 = blockIdx.x * 128;
  int la = lane & 15, ko = (lane >> 4) * 8;
  // staging chunk ids: q = tid + it*256; row = q>>2, kcol = (q&3)*8.
  // LDS byte offset q*16 = wave-uniform base + lane*16 (global_load_lds contract).
  int q0 = tid, q1 = tid + 256;
  int r0 = q0 >> 2, c0 = (q0 & 3) * 8;
  int r1 = q1 >> 2, c1 = (q1 & 3) * 8;
  f32x4 acc[4][4] = {};
  for (int k0 = 0; k0 < K; k0 += 32){
    __builtin_amdgcn_global_load_lds(
      (const __attribute__((address_space(1))) void*)(A  + (size_t)(m0+r0)*K + k0 + c0),
      (__attribute__((address_space(3))) void*)(As + q0*8), 16, 0, 0);
    __builtin_amdgcn_global_load_lds(
      (const __attribute__((address_space(1))) void*)(A  + (size_t)(m0+r1)*K + k0 + c1),
      (__attribute__((address_space(3))) void*)(As + q1*8), 16, 0, 0);
    __builtin_amdgcn_global_load_lds(
      (const __attribute__((address_space(1))) void*)(BT + (size_t)(n0+r0)*K + k0 + c0),
      (__attribute__((address_space(3))) void*)(Bs + q0*8), 16, 0, 0);
    __builtin_amdgcn_global_load_lds(
      (const __attribute__((address_space(1))) void*)(BT + (size_t)(n0+r1)*K + k0 + c1),
      (__attribute__((address_space(3))) void*)(Bs + q1*8), 16, 0, 0);
    __syncthreads();                  // compiler drains vmcnt before s_barrier
    short8 av[4], bv[4];
    #pragma unroll
    for (int f = 0; f < 4; ++f){
      av[f] = *(const short8*)&As[(wr + f*16 + la)*32 + ko];
      bv[f] = *(const short8*)&Bs[(wc + f*16 + la)*32 + ko];
    }
    #pragma unroll
    for (int mf = 0; mf < 4; ++mf)
      #pragma unroll
      for (int nf = 0; nf < 4; ++nf)
        acc[mf][nf] = __builtin_amdgcn_mfma_f32_16x16x32_bf16(av[mf], bv[nf], acc[mf][nf], 0, 0, 0);
    __syncthreads();
  }
  int dr = (lane >> 4) * 4, dc = lane & 15;
  #pragma unroll
  for (int mf = 0; mf < 4; ++mf){
    #pragma unroll
    for (int nf = 0; nf < 4; ++nf){
      int col = n0 + wc + nf*16 + dc;
      if (col >= Nreal) continue;
      float bb = bias[col];
      #pragma unroll
      for (int rg = 0; rg < 4; ++rg){
        int row = m0 + wr + mf*16 + dr + rg;
        float v = acc[mf][nf][rg] + bb;
        if (OUT_BF16) ((unsigned short*)C)[(size_t)row*ldc + col] = f2bf(v);
        else          ((float*)C)[(size_t)row*ldc + col] = v;
      }
    }
  }
}

// pin 8 short8 values live-in-register (single asm: one waitcnt, no interleave)
#define PIN8(a) asm volatile("" : "+v"((a)[0]),"+v"((a)[1]),"+v"((a)[2]),"+v"((a)[3]), \
                                   "+v"((a)[4]),"+v"((a)[5]),"+v"((a)[6]),"+v"((a)[7]))

// ---------- persistent scan: 16 colocated workers (r10 verbatim — PASS @1110us) ----------
__global__ __launch_bounds__(256, 1) void k_scan(
    const unsigned short* __restrict__ UT,   // [HID][HID] bf16, UT[n][k]
    const float* __restrict__ G0,            // [ROWS][HID] fp32 (includes b_gate)
    unsigned short* __restrict__ Hfull,      // [(32+ROWS)][HID] bf16, rows 0..31 zeroed
    int* ctrl){
  __shared__ float red[4][32][RST];          // 34 KB
  __shared__ float ldspad[13312];            // 52 KB occupancy limiter: 1 block/CU
  __shared__ int s_slot, s_fast;
  const int tid  = threadIdx.x;
  const int lane = tid & 63, wid = tid >> 6;

  // ---- election (leader-XCD preference + timeout fallback) ----
  if (tid == 0){
    int xcc;
    asm volatile("s_getreg_b32 %0, hwreg(HW_REG_XCC_ID)" : "=s"(xcc));
    xcc &= 0xff;
    int expected = 0;
    __hip_atomic_compare_exchange_strong(&ctrl[0], &expected, xcc + 1,
        __ATOMIC_ACQ_REL, __ATOMIC_ACQUIRE, __HIP_MEMORY_SCOPE_AGENT);
    int lead = (expected == 0) ? xcc : expected - 1;
    int ticket = -1;
    if (xcc == lead){
      ticket = __hip_atomic_fetch_add(&ctrl[32], 1, __ATOMIC_RELAXED, __HIP_MEMORY_SCOPE_AGENT);
    } else {
      for (int it = 0; it < 64; ++it){
        if (__hip_atomic_load(&ctrl[32], __ATOMIC_RELAXED, __HIP_MEMORY_SCOPE_AGENT) >= SNBLK) break;
        for (int j = 0; j < 4; ++j) __builtin_amdgcn_s_sleep(32);
      }
      if (__hip_atomic_load(&ctrl[32], __ATOMIC_RELAXED, __HIP_MEMORY_SCOPE_AGENT) < SNBLK)
        ticket = __hip_atomic_fetch_add(&ctrl[32], 1, __ATOMIC_RELAXED, __HIP_MEMORY_SCOPE_AGENT);
    }
    int slot = (ticket >= 0 && ticket < SNBLK) ? ticket : -1;
    int fast = 1;
    if (slot >= 0){
      __hip_atomic_store(&ctrl[PB + slot], xcc + 1, __ATOMIC_RELEASE, __HIP_MEMORY_SCOPE_AGENT);
      for (int i = 0; i < SNBLK; ++i){
        int v;
        while ((v = __hip_atomic_load(&ctrl[PB + i], __ATOMIC_ACQUIRE, __HIP_MEMORY_SCOPE_AGENT)) == 0)
          __builtin_amdgcn_s_sleep(8);
        if (v - 1 != xcc) fast = 0;
      }
    }
    s_slot = slot; s_fast = fast;
  }
  __syncthreads();
  const int slot = s_slot, fastp = s_fast;
  if (slot == -977) ldspad[tid] = (float)tid;   // keeps pad allocated; never true
  if (slot < 0) return;
  const int n0 = slot * 64;

  const int q  = wid;                  // this wave's K-quarter
  const int la = lane & 15, kg = lane >> 4;
  const int b  = tid >> 3, nn = (tid & 7) * 8;

  // ---- B preload ONCE + per-iteration pin ----
  short8 Br[4][8];                     // [col-group][kc]
  #pragma unroll
  for (int cg = 0; cg < 4; ++cg)
    #pragma unroll
    for (int kc = 0; kc < 8; ++kc)
      Br[cg][kc] = *(const short8*)(UT + (size_t)(n0 + cg*16 + la)*HID + q*256 + kc*32 + kg*8);

  float creg[8];
  #pragma unroll
  for (int j = 0; j < 8; ++j) creg[j] = 0.f;
  float g0r[8];
  {
    const float* gp = G0 + (size_t)b * HID + n0 + nn;
    float4 lo = *(const float4*)gp, hi = *(const float4*)(gp + 4);
    g0r[0]=lo.x; g0r[1]=lo.y; g0r[2]=lo.z; g0r[3]=lo.w;
    g0r[4]=hi.x; g0r[5]=hi.y; g0r[6]=hi.z; g0r[7]=hi.w;
  }

  for (int t = 0; t < SEQ; ++t){
    PIN8(Br[0]); PIN8(Br[1]); PIN8(Br[2]); PIN8(Br[3]);

    // ---- wait for peers' h_{t-1}: wave0 polls 64 flags; others park at barrier ----
    if (t > 0){
      if (wid == 0){
        const int* fp = &ctrl[FB + (lane & 15)*64 + (lane >> 4)*16];
        int guard = 0, dead = 0;
        for (;;){
          int v = __hip_atomic_load(fp, __ATOMIC_RELAXED, __HIP_MEMORY_SCOPE_AGENT);
          if (__all(v >= t)) break;
          if (++guard > (1<<15)) { dead = 1; break; }
        }
        if (dead && lane == 0)
          __hip_atomic_fetch_or(&ctrl[64], 1, __ATOMIC_RELAXED, __HIP_MEMORY_SCOPE_AGENT);
        if (!fastp) __threadfence();       // slow path: inv before remote h-reads
      }
      __syncthreads();                     // also orders gates-reads(t-1) vs red-writes(t)
    }

    // ---- A-loads: 16 b128 in one MLP burst + single batch pin ----
    const unsigned short* hpA = Hfull + (size_t)t*32*HID + (size_t)la*HID + q*256 + kg*8;
    const unsigned short* hpB = hpA + (size_t)16*HID;
    short8 A0[8], A1[8];
    #pragma unroll
    for (int kc = 0; kc < 8; ++kc){
      A0[kc] = *(const short8*)(hpA + kc*32);
      A1[kc] = *(const short8*)(hpB + kc*32);
    }
    asm volatile("" : "+v"(A0[0]),"+v"(A0[1]),"+v"(A0[2]),"+v"(A0[3]),
                      "+v"(A0[4]),"+v"(A0[5]),"+v"(A0[6]),"+v"(A0[7]),
                      "+v"(A1[0]),"+v"(A1[1]),"+v"(A1[2]),"+v"(A1[3]),
                      "+v"(A1[4]),"+v"(A1[5]),"+v"(A1[6]),"+v"(A1[7]));

    // ---- G0 prefetch for next step: issued now, completes under MFMA+gates ----
    float4 gnlo, gnhi;
    {
      int tn = (t + 1 < SEQ) ? (t + 1) : t;
      const float* gp = G0 + ((size_t)tn*32 + b) * HID + n0 + nn;
      gnlo = *(const float4*)gp; gnhi = *(const float4*)(gp + 4);
    }

    // ---- pure-register MFMA stream: 64 MFMA, no memory ops ----
    f32x4 acc0[4] = {}, acc1[4] = {};
    #pragma unroll
    for (int kc = 0; kc < 8; ++kc)
      #pragma unroll
      for (int cg = 0; cg < 4; ++cg){
        acc0[cg] = __builtin_amdgcn_mfma_f32_16x16x32_bf16(A0[kc], Br[cg][kc], acc0[cg], 0, 0, 0);
        acc1[cg] = __builtin_amdgcn_mfma_f32_16x16x32_bf16(A1[kc], Br[cg][kc], acc1[cg], 0, 0, 0);
      }

    // ---- K-quarter partials -> red ----
    #pragma unroll
    for (int cg = 0; cg < 4; ++cg)
      #pragma unroll
      for (int rg = 0; rg < 4; ++rg){
        red[q][kg*4 + rg][cg*16 + la]      = acc0[cg][rg];
        red[q][16 + kg*4 + rg][cg*16 + la] = acc1[cg][rg];
      }
    __syncthreads();

    // ---- gates: 4-quarter sum + fast sigmoid/tanh; h-write ----
    float4 q0lo = *(const float4*)&red[0][b][nn], q0hi = *(const float4*)&red[0][b][nn+4];
    float4 q1lo = *(const float4*)&red[1][b][nn], q1hi = *(const float4*)&red[1][b][nn+4];
    float4 q2lo = *(const float4*)&red[2][b][nn], q2hi = *(const float4*)&red[2][b][nn+4];
    float4 q3lo = *(const float4*)&red[3][b][nn], q3hi = *(const float4*)&red[3][b][nn+4];
    float gg[8] = {
      q0lo.x+q1lo.x+q2lo.x+q3lo.x+g0r[0], q0lo.y+q1lo.y+q2lo.y+q3lo.y+g0r[1],
      q0lo.z+q1lo.z+q2lo.z+q3lo.z+g0r[2], q0lo.w+q1lo.w+q2lo.w+q3lo.w+g0r[3],
      q0hi.x+q1hi.x+q2hi.x+q3hi.x+g0r[4], q0hi.y+q1hi.y+q2hi.y+q3hi.y+g0r[5],
      q0hi.z+q1hi.z+q2hi.z+q3hi.z+g0r[6], q0hi.w+q1hi.w+q2hi.w+q3hi.w+g0r[7] };
    short8 hv;
    #pragma unroll
    for (int j = 0; j < 8; ++j){
      float g  = gg[j];
      float e  = __expf(-g);
      float s  = __builtin_amdgcn_rcpf(1.f + e);
      float e2 = e * e;
      float tg = 2.f * __builtin_amdgcn_rcpf(1.f + e2) - 1.f;
      float cn = s * (creg[j] + tg);
      creg[j] = cn;
      float ec = __expf(-2.f * cn);
      float th = 2.f * __builtin_amdgcn_rcpf(1.f + ec) - 1.f;
      hv[j] = (short)f2bf(th * s);
    }
    *(short8*)(Hfull + ((size_t)(t+1)*32 + b) * HID + n0 + nn) = hv;

    // ---- per-wave flag after own h-stores drained ----
    asm volatile("s_waitcnt vmcnt(0)" ::: "memory");
    if (!fastp) __threadfence();
    if (lane == 0)
      __hip_atomic_store(&ctrl[FB + slot*64 + wid*16], t + 1,
                         __ATOMIC_RELAXED, __HIP_MEMORY_SCOPE_AGENT);

    g0r[0]=gnlo.x; g0r[1]=gnlo.y; g0r[2]=gnlo.z; g0r[3]=gnlo.w;
    g0r[4]=gnhi.x; g0r[5]=gnhi.y; g0r[6]=gnhi.z; g0r[7]=gnhi.w;
  }

  // telemetry: slow path +1ms, any deadman +4ms (visible in dur_us)
  if (slot == 0 && tid == 0){
    long long spin = 0;
    if (!fastp) spin += 100000LL;
    if (__hip_atomic_load(&ctrl[64], __ATOMIC_RELAXED, __HIP_MEMORY_SCOPE_AGENT) != 0)
      spin += 400000LL;
    if (spin){
      long long t0 = __builtin_amdgcn_s_memrealtime();
      while (__builtin_amdgcn_s_memrealtime() - t0 < spin) {}
    }
  }
}

extern "C" void kernel_launch(void* const* d_in, const int* in_sizes, int n_in,
                              void* d_out, int out_size, void* d_ws, size_t ws_size,
                              hipStream_t stream){
  (void)in_sizes; (void)n_in; (void)out_size;
  const int*   seq     = (const int*)d_in[0];
  const float* emb     = (const float*)d_in[1];
  const float* w_gate  = (const float*)d_in[2];
  const float* b_gate  = (const float*)d_in[3];
  const float* w_out   = (const float*)d_in[4];
  const float* b_out   = (const float*)d_in[5];
  const float* w_dense = (const float*)d_in[6];
  const float* b_dense = (const float*)d_in[7];
  float* out = (float*)d_out;

  const int NPAD_D = 10112;   // 79 * 128
  char* ws = (char*)d_ws;
  size_t off = 0;
  auto alloc = [&](size_t bytes){ size_t o = off; off += (bytes + 255) & ~(size_t)255; return o; };
  size_t off_W1T = alloc((size_t)2*HID*HID);
  size_t off_UT  = alloc((size_t)2*HID*HID);
  size_t off_WoT = alloc((size_t)2*HID*HID);
  size_t off_WdT = alloc((size_t)2*NPAD_D*HID);
  size_t off_X   = alloc((size_t)2*ROWS*EMB);             // bf16; reused as YS
  size_t off_G0  = alloc((size_t)4*ROWS*HID);
  size_t off_H   = alloc((size_t)2*(ROWS+32)*HID);
  size_t off_ctl = alloc(8192);
  if (ws_size < off) return;

  unsigned short* W1T = (unsigned short*)(ws + off_W1T);
  unsigned short* UT  = (unsigned short*)(ws + off_UT);
  unsigned short* WoT = (unsigned short*)(ws + off_WoT);
  unsigned short* WdT = (unsigned short*)(ws + off_WdT);
  unsigned short* X   = (unsigned short*)(ws + off_X);
  unsigned short* YS  = (unsigned short*)(ws + off_X);
  float*          G0  = (float*)(ws + off_G0);
  unsigned short* Hf  = (unsigned short*)(ws + off_H);
  int*            ctl = (int*)(ws + off_ctl);

  hipMemsetAsync(ctl, 0, 8192, stream);
  hipMemsetAsync(WdT + (size_t)10000*HID, 0, (size_t)2*(NPAD_D-10000)*HID, stream);
  hipMemsetAsync(Hf, 0, (size_t)2*32*HID, stream);

  k_transpose<<<dim3(16,16), 256, 0, stream>>>(w_gate,           W1T, HID, HID);
  k_transpose<<<dim3(16,16), 256, 0, stream>>>(w_gate + HID*HID, UT,  HID, HID);
  k_transpose<<<dim3(16,16), 256, 0, stream>>>(w_out,            WoT, HID, HID);
  k_transpose<<<dim3(157,16),256, 0, stream>>>(w_dense,          WdT, HID, VOCAB);

  k_gather<<<ROWS, 256, 0, stream>>>(seq, emb, X);

  // G0 = X @ W1 + b_gate  (fp32 out)
  k_gemm_bt<false><<<dim3(8,64), 256, 0, stream>>>(X, W1T, b_gate, G0, ROWS, HID, EMB, HID);

  // sequential scan (16 workers elected from 256 candidate blocks) — r10 verbatim
  k_scan<<<256, 256, 0, stream>>>(UT, G0, Hf, ctl);

  // ys = H @ w_out + b_out  (bf16 out, into X region)
  k_gemm_bt<true><<<dim3(8,64), 256, 0, stream>>>(Hf + (size_t)32*HID, WoT, b_out, YS,
                                                  ROWS, HID, HID, HID);

  // logits = ys @ w_dense + b_dense (fp32 out)
  k_gemm_bt<false><<<dim3(79,64), 256, 0, stream>>>(YS, WdT, b_dense, out,
                                                    ROWS, VOCAB, HID, VOCAB);
}